// Round 1
// baseline (2366.872 us; speedup 1.0000x reference)
//
#include <hip/hip_runtime.h>
#include <math.h>

// EntropicNeuralQuantileRegression on MI355X (gfx950)
// n=m=1024, F=64, R=8, H=128, EPS=0.1
//
// Decomposition: layer0 pre-activation = A[i] + Bu[j], with
//   A  = X @ W0[:64,:]            [1024,128]
//   Bu = U @ W0[64:72,:] + b0     [1024,128]
// Then per pair: h0=sp(A+Bu); h1=sp(h0@W1+b1); h2=sp(h1@W2+b2);
// phi=h2@Wout+bout; slack=Y[i].U[j]-phi; psi[i]=logsumexp_j.
//
// Round 1: correctness-first fp32 VALU implementation (no fp32 MFMA on CDNA4).
// W1/W2 staged as bf16 in LDS (64KB -> 2 blocks/CU).

__device__ __forceinline__ float softplus_f(float x) {
    // stable: max(x,0) + log1p(exp(-|x|))  (matches jax.nn.softplus)
    return fmaxf(x, 0.0f) + log1pf(__expf(-fabsf(x)));
}

__device__ __forceinline__ unsigned short f2bf(float x) {
    unsigned int u = __float_as_uint(x);
    u = (u + 0x7FFFu + ((u >> 16) & 1u)) >> 16;   // RNE
    return (unsigned short)u;
}

__device__ __forceinline__ float bf2f(unsigned short b) {
    return __uint_as_float(((unsigned int)b) << 16);
}

// ---------------- prep: A, Bu, bf16 weight packs ----------------
__global__ __launch_bounds__(128) void prep_kernel(
    const float* __restrict__ X, const float* __restrict__ U,
    const float* __restrict__ W0, const float* __restrict__ b0,
    const float* __restrict__ W1, const float* __restrict__ W2,
    float* __restrict__ A, float* __restrict__ Bu,
    unsigned short* __restrict__ w1b, unsigned short* __restrict__ w2b)
{
    const int b = blockIdx.x, t = threadIdx.x;
    if (b < 1024) {                       // A row b: X[b,:64] @ W0[:64, t]
        const float* xr = X + b * 64;
        float s = 0.f;
        #pragma unroll 8
        for (int f = 0; f < 64; ++f) s += xr[f] * W0[f * 128 + t];
        A[b * 128 + t] = s;
    } else if (b < 2048) {                // Bu row j: U[j,:8] @ W0[64:72, t] + b0[t]
        const int j = b - 1024;
        const float* ur = U + j * 8;
        float s = b0[t];
        #pragma unroll
        for (int r = 0; r < 8; ++r) s += ur[r] * W0[(64 + r) * 128 + t];
        Bu[j * 128 + t] = s;
    } else if (b < 2176) {                // W1 -> bf16
        const int idx = (b - 2048) * 128 + t;
        w1b[idx] = f2bf(W1[idx]);
    } else {                              // W2 -> bf16
        const int idx = (b - 2176) * 128 + t;
        w2b[idx] = f2bf(W2[idx]);
    }
}

// ---------------- main: MLP over pair tiles + partial logsumexp ----------------
// grid = 1024 i-rows x 4 j-chunks (256 js each). block = 256 threads:
//   o = tid & 127 : output-feature lane, g = tid >> 7 : pair-group (8 pairs each)
// Per round (16 pairs): layer GEMVs read h from LDS [g][k][p] (broadcast float4)
// and bf16 weights from LDS [k][o] (stride-2B, conflict-free).
__global__ __launch_bounds__(256, 2) void main_kernel(
    const float* __restrict__ A, const float* __restrict__ Bu,
    const unsigned short* __restrict__ w1b, const unsigned short* __restrict__ w2b,
    const float* __restrict__ Y, const float* __restrict__ U,
    const float* __restrict__ b1, const float* __restrict__ b2,
    const float* __restrict__ Wout, const float* __restrict__ bout,
    float* __restrict__ part)
{
    __shared__ unsigned short w1_lds[128 * 128];   // 32 KB
    __shared__ unsigned short w2_lds[128 * 128];   // 32 KB
    __shared__ float h_lds[2][128][8];             // 8 KB  (ping-pong via syncs)
    __shared__ float slack_lds[256];               // 1 KB
    __shared__ float red_lds[4][8];
    __shared__ float redw[4];

    const int tid = threadIdx.x;
    const int o   = tid & 127;
    const int g   = tid >> 7;
    const int i   = blockIdx.x >> 2;
    const int c   = blockIdx.x & 3;
    const int j0  = c * 256;

    {   // stage bf16 weights to LDS, 16B per thread-iter
        const uint4* s1 = (const uint4*)w1b;
        const uint4* s2 = (const uint4*)w2b;
        uint4* d1 = (uint4*)w1_lds;
        uint4* d2 = (uint4*)w2_lds;
        for (int idx = tid; idx < 2048; idx += 256) { d1[idx] = s1[idx]; d2[idx] = s2[idx]; }
    }

    const float aO  = A[i * 128 + o];
    const float rb1 = b1[o];
    const float rb2 = b2[o];
    const float rwo = Wout[o];
    const float bo  = bout[0];
    float yreg[8];
    #pragma unroll
    for (int r = 0; r < 8; ++r) yreg[r] = Y[i * 8 + r];

    __syncthreads();

    for (int rd = 0; rd < 16; ++rd) {
        const int jb = j0 + rd * 16 + g * 8;

        // ---- layer 0 (decomposed) ----
        {
            float hv[8];
            #pragma unroll
            for (int p = 0; p < 8; ++p)
                hv[p] = softplus_f(aO + Bu[(jb + p) * 128 + o]);
            float4* dst = (float4*)&h_lds[g][o][0];
            dst[0] = make_float4(hv[0], hv[1], hv[2], hv[3]);
            dst[1] = make_float4(hv[4], hv[5], hv[6], hv[7]);
        }
        __syncthreads();

        float acc[8];
        // ---- layer 1 ----
        #pragma unroll
        for (int p = 0; p < 8; ++p) acc[p] = rb1;
        #pragma unroll 4
        for (int k = 0; k < 128; ++k) {
            const float w = bf2f(w1_lds[k * 128 + o]);
            const float4* hp = (const float4*)&h_lds[g][k][0];
            const float4 ha = hp[0], hb = hp[1];
            acc[0] += ha.x * w; acc[1] += ha.y * w; acc[2] += ha.z * w; acc[3] += ha.w * w;
            acc[4] += hb.x * w; acc[5] += hb.y * w; acc[6] += hb.z * w; acc[7] += hb.w * w;
        }
        __syncthreads();   // all reads of h0 done
        {
            float hv[8];
            #pragma unroll
            for (int p = 0; p < 8; ++p) hv[p] = softplus_f(acc[p]);
            float4* dst = (float4*)&h_lds[g][o][0];
            dst[0] = make_float4(hv[0], hv[1], hv[2], hv[3]);
            dst[1] = make_float4(hv[4], hv[5], hv[6], hv[7]);
        }
        __syncthreads();

        // ---- layer 2 ----
        #pragma unroll
        for (int p = 0; p < 8; ++p) acc[p] = rb2;
        #pragma unroll 4
        for (int k = 0; k < 128; ++k) {
            const float w = bf2f(w2_lds[k * 128 + o]);
            const float4* hp = (const float4*)&h_lds[g][k][0];
            const float4 ha = hp[0], hb = hp[1];
            acc[0] += ha.x * w; acc[1] += ha.y * w; acc[2] += ha.z * w; acc[3] += ha.w * w;
            acc[4] += hb.x * w; acc[5] += hb.y * w; acc[6] += hb.z * w; acc[7] += hb.w * w;
        }

        // ---- output layer: phi = sum_o h2[o]*Wout[o] + bout ----
        float ph[8];
        #pragma unroll
        for (int p = 0; p < 8; ++p) {
            float x = softplus_f(acc[p]) * rwo;
            #pragma unroll
            for (int off = 32; off > 0; off >>= 1) x += __shfl_down(x, off);
            ph[p] = x;
        }
        const int wid = tid >> 6;
        if ((tid & 63) == 0) {
            #pragma unroll
            for (int p = 0; p < 8; ++p) red_lds[wid][p] = ph[p];
        }
        __syncthreads();
        if (tid < 16) {   // one thread per pair of this round
            const int gg = tid >> 3, p = tid & 7;
            const float phi = red_lds[2 * gg][p] + red_lds[2 * gg + 1][p] + bo;
            const int j = j0 + rd * 16 + tid;
            float cost = 0.f;
            #pragma unroll
            for (int r = 0; r < 8; ++r) cost += yreg[r] * U[j * 8 + r];
            slack_lds[rd * 16 + tid] = cost - phi;
        }
        __syncthreads();
    }

    // ---- partial logsumexp over this block's 256 slacks ----
    const float v = slack_lds[tid];
    float mx = v;
    #pragma unroll
    for (int off = 32; off > 0; off >>= 1) mx = fmaxf(mx, __shfl_xor(mx, off));
    if ((tid & 63) == 0) redw[tid >> 6] = mx;
    __syncthreads();
    mx = fmaxf(fmaxf(redw[0], redw[1]), fmaxf(redw[2], redw[3]));
    float e = __expf((v - mx) * 10.0f);
    #pragma unroll
    for (int off = 32; off > 0; off >>= 1) e += __shfl_xor(e, off);
    __syncthreads();   // redw reuse
    if ((tid & 63) == 0) redw[tid >> 6] = e;
    __syncthreads();
    if (tid == 0) {
        const float S = redw[0] + redw[1] + redw[2] + redw[3];
        part[(i * 4 + c) * 2 + 0] = mx;
        part[(i * 4 + c) * 2 + 1] = S;
    }
}

// ---------------- combine: merge 4 chunk partials per row ----------------
__global__ __launch_bounds__(256) void combine_kernel(
    const float* __restrict__ part, float* __restrict__ out)
{
    const int i = blockIdx.x * 256 + threadIdx.x;
    if (i >= 1024) return;
    float m[4], s[4];
    #pragma unroll
    for (int cc = 0; cc < 4; ++cc) {
        m[cc] = part[(i * 4 + cc) * 2 + 0];
        s[cc] = part[(i * 4 + cc) * 2 + 1];
    }
    const float M = fmaxf(fmaxf(m[0], m[1]), fmaxf(m[2], m[3]));
    float S = 0.f;
    #pragma unroll
    for (int cc = 0; cc < 4; ++cc) S += s[cc] * __expf((m[cc] - M) * 10.0f);
    // psi = M + EPS*(log(S) - log(1024))
    out[i] = M + 0.1f * (logf(S) - 6.9314718055994531f);
}

extern "C" void kernel_launch(void* const* d_in, const int* in_sizes, int n_in,
                              void* d_out, int out_size, void* d_ws, size_t ws_size,
                              hipStream_t stream) {
    const float* X    = (const float*)d_in[0];
    const float* Y    = (const float*)d_in[1];
    const float* U    = (const float*)d_in[2];
    const float* W0   = (const float*)d_in[3];
    const float* b0   = (const float*)d_in[4];
    const float* W1   = (const float*)d_in[5];
    const float* b1   = (const float*)d_in[6];
    const float* W2   = (const float*)d_in[7];
    const float* b2   = (const float*)d_in[8];
    const float* Wout = (const float*)d_in[9];
    const float* bout = (const float*)d_in[10];
    float* out = (float*)d_out;

    char* ws = (char*)d_ws;
    float*          A    = (float*)(ws);                                  // 512 KB
    float*          Bu   = (float*)(ws + (512 << 10));                    // 512 KB
    unsigned short* w1b  = (unsigned short*)(ws + (1024 << 10));          // 32 KB
    unsigned short* w2b  = (unsigned short*)(ws + (1024 << 10) + (32 << 10)); // 32 KB
    float*          part = (float*)(ws + (1024 << 10) + (64 << 10));      // 32 KB

    prep_kernel<<<2304, 128, 0, stream>>>(X, U, W0, b0, W1, W2, A, Bu, w1b, w2b);
    main_kernel<<<4096, 256, 0, stream>>>(A, Bu, w1b, w2b, Y, U, b1, b2, Wout, bout, part);
    combine_kernel<<<4, 256, 0, stream>>>(part, out);
}

// Round 3
// 359.504 us; speedup vs baseline: 6.5837x; 6.5837x over previous
//
#include <hip/hip_runtime.h>
#include <math.h>

// EntropicNeuralQuantileRegression on MI355X (gfx950) — MFMA version.
// n=m=1024, F=64, R=8, H=128, EPS=0.1
//
//   A  = X @ W0[:64,:]            [1024,128] f32   (prep)
//   Bu = U @ W0[64:72,:] + b0     [1024,128] f32   (prep)
//   W1T/W2T = transposed bf16 weights [n][k]        (prep)
// Main: per (16 i x 64 j) block, 16 rounds of (1 i x 64 j):
//   h0 = sp(A[i]+Bu[j])  (VALU, Bu in regs)  -> Ha (bf16, padded)
//   h1 = sp(h0 @ W1 + b1)  via mfma_f32_16x16x32_bf16, N-split across 4 waves,
//        weights preloaded as B-fragments in VGPRs  -> Hb
//   h2 = sp(h1 @ W2 + b2)  -> Ha
//   phi = h2 @ Wout + bout; slack = Y.U - phi; per-round 64-j logsumexp partial.

typedef __attribute__((ext_vector_type(8))) short short8;
typedef __attribute__((ext_vector_type(4))) float f32x4;

__device__ __forceinline__ float softplus_f(float x) {
    float ax = fabsf(x);
    float t = __logf(1.0f + __expf(-ax));
    return fmaxf(x, 0.0f) + t;
}

__device__ __forceinline__ unsigned short f2bf(float x) {
    unsigned int u = __float_as_uint(x);
    u = (u + 0x7FFFu + ((u >> 16) & 1u)) >> 16;   // RNE
    return (unsigned short)u;
}

__device__ __forceinline__ float bf2f(unsigned short b) {
    return __uint_as_float(((unsigned int)b) << 16);
}

// ---------------- prep: A, Bu, transposed bf16 weights ----------------
__global__ __launch_bounds__(128) void prep_kernel(
    const float* __restrict__ X, const float* __restrict__ U,
    const float* __restrict__ W0, const float* __restrict__ b0,
    const float* __restrict__ W1, const float* __restrict__ W2,
    float* __restrict__ A, float* __restrict__ Bu,
    unsigned short* __restrict__ w1t, unsigned short* __restrict__ w2t)
{
    const int b = blockIdx.x, t = threadIdx.x;
    if (b < 1024) {                       // A row b: X[b,:64] @ W0[:64, t]
        const float* xr = X + b * 64;
        float s = 0.f;
        #pragma unroll 8
        for (int f = 0; f < 64; ++f) s += xr[f] * W0[f * 128 + t];
        A[b * 128 + t] = s;
    } else if (b < 2048) {                // Bu row j: U[j,:8] @ W0[64:72, t] + b0[t]
        const int j = b - 1024;
        const float* ur = U + j * 8;
        float s = b0[t];
        #pragma unroll
        for (int r = 0; r < 8; ++r) s += ur[r] * W0[(64 + r) * 128 + t];
        Bu[j * 128 + t] = s;
    } else if (b < 2176) {                // W1T[n][k] = bf16(W1[k][n])
        const int n = b - 2048;
        w1t[n * 128 + t] = f2bf(W1[t * 128 + n]);
    } else {                              // W2T[n][k] = bf16(W2[k][n])
        const int n = b - 2176;
        w2t[n * 128 + t] = f2bf(W2[t * 128 + n]);
    }
}

// ---------------- main ----------------
__global__ __launch_bounds__(256, 2) void main_kernel(
    const float* __restrict__ A, const float* __restrict__ Bu,
    const unsigned short* __restrict__ w1t, const unsigned short* __restrict__ w2t,
    const float* __restrict__ Y, const float* __restrict__ U,
    const float* __restrict__ b1, const float* __restrict__ b2,
    const float* __restrict__ Wout, const float* __restrict__ bout,
    float* __restrict__ part)
{
    __shared__ __align__(16) unsigned short Ha[64][136];   // 17.0 KB (pad: stride 272B)
    __shared__ __align__(16) unsigned short Hb[64][136];   // 17.0 KB
    __shared__ __align__(16) float A_lds[16][128];         // 8 KB
    __shared__ __align__(16) float U_lds[64][8];           // 2 KB
    __shared__ __align__(16) float Y_lds[16][8];           // 0.5 KB
    __shared__ float slk[64];

    const int tid  = threadIdx.x;
    const int lane = tid & 63;
    const int w    = tid >> 6;          // wave 0..3, owns out-cols [32w, 32w+32)
    const int ib   = blockIdx.x >> 4;
    const int jb   = blockIdx.x & 15;
    const int i0   = ib * 16;
    const int j0   = jb * 64;
    const int p    = tid >> 2;          // pair (j_loc) for L0/phi stages
    const int q    = tid & 3;           // 32-col quarter for L0/phi stages

    // ---- stage A tile, U tile, Y tile ----
    {
        const float4* src = (const float4*)(A + i0 * 128);
        float4* dst = (float4*)(&A_lds[0][0]);
        dst[tid] = src[tid];
        dst[tid + 256] = src[tid + 256];
        if (tid < 128) ((float4*)U_lds)[tid] = ((const float4*)(U + j0 * 8))[tid];
        else if (tid < 160) ((float4*)Y_lds)[tid - 128] = ((const float4*)(Y + i0 * 8))[tid - 128];
    }

    // ---- Bu slice for this thread's (pair, quarter): constant across rounds ----
    float bu_reg[32];
    {
        const float4* src = (const float4*)(Bu + (j0 + p) * 128 + q * 32);
        #pragma unroll
        for (int v = 0; v < 8; ++v) {
            float4 f = src[v];
            bu_reg[v * 4 + 0] = f.x; bu_reg[v * 4 + 1] = f.y;
            bu_reg[v * 4 + 2] = f.z; bu_reg[v * 4 + 3] = f.w;
        }
    }

    // ---- preload weight B-fragments (this wave's 32-col slice) ----
    short8 wf[2][2][4];     // [layer][n-tile][k-step]
    {
        const int col = lane & 15;
        const int kk  = (lane >> 4) * 8;
        #pragma unroll
        for (int nt = 0; nt < 2; ++nt)
            #pragma unroll
            for (int ks = 0; ks < 4; ++ks) {
                wf[0][nt][ks] = *(const short8*)(w1t + (w * 32 + nt * 16 + col) * 128 + ks * 32 + kk);
                wf[1][nt][ks] = *(const short8*)(w2t + (w * 32 + nt * 16 + col) * 128 + ks * 32 + kk);
            }
    }
    float rb1[2], rb2[2];
    rb1[0] = b1[w * 32 + (lane & 15)];      rb1[1] = b1[w * 32 + 16 + (lane & 15)];
    rb2[0] = b2[w * 32 + (lane & 15)];      rb2[1] = b2[w * 32 + 16 + (lane & 15)];
    const float bo = bout[0];

    __syncthreads();

    for (int rd = 0; rd < 16; ++rd) {
        // ======== layer 0: h0 = sp(A[i] + Bu[j]) -> Ha ========
        {
            const float* ar = &A_lds[rd][q * 32];
            unsigned short hv[32];
            #pragma unroll
            for (int e = 0; e < 32; ++e)
                hv[e] = f2bf(softplus_f(ar[e] + bu_reg[e]));
            short8* dst = (short8*)&Ha[p][q * 32];
            #pragma unroll
            for (int v = 0; v < 4; ++v) dst[v] = ((short8*)hv)[v];
        }
        __syncthreads();

        // ======== layer 1: Ha -> Hb ========
        {
            f32x4 acc[4][2];
            #pragma unroll
            for (int mt = 0; mt < 4; ++mt) {
                acc[mt][0] = (f32x4){rb1[0], rb1[0], rb1[0], rb1[0]};
                acc[mt][1] = (f32x4){rb1[1], rb1[1], rb1[1], rb1[1]};
            }
            const int col = lane & 15, kk = (lane >> 4) * 8;
            #pragma unroll
            for (int ks = 0; ks < 4; ++ks) {
                short8 a[4];
                #pragma unroll
                for (int mt = 0; mt < 4; ++mt)
                    a[mt] = *(const short8*)&Ha[mt * 16 + col][ks * 32 + kk];
                #pragma unroll
                for (int mt = 0; mt < 4; ++mt) {
                    acc[mt][0] = __builtin_amdgcn_mfma_f32_16x16x32_bf16(a[mt], wf[0][0][ks], acc[mt][0], 0, 0, 0);
                    acc[mt][1] = __builtin_amdgcn_mfma_f32_16x16x32_bf16(a[mt], wf[0][1][ks], acc[mt][1], 0, 0, 0);
                }
            }
            const int crow = (lane >> 4) * 4;
            #pragma unroll
            for (int mt = 0; mt < 4; ++mt)
                #pragma unroll
                for (int nt = 0; nt < 2; ++nt)
                    #pragma unroll
                    for (int r = 0; r < 4; ++r)
                        Hb[mt * 16 + crow + r][w * 32 + nt * 16 + col] = f2bf(softplus_f(acc[mt][nt][r]));
        }
        __syncthreads();

        // ======== layer 2: Hb -> Ha ========
        {
            f32x4 acc[4][2];
            #pragma unroll
            for (int mt = 0; mt < 4; ++mt) {
                acc[mt][0] = (f32x4){rb2[0], rb2[0], rb2[0], rb2[0]};
                acc[mt][1] = (f32x4){rb2[1], rb2[1], rb2[1], rb2[1]};
            }
            const int col = lane & 15, kk = (lane >> 4) * 8;
            #pragma unroll
            for (int ks = 0; ks < 4; ++ks) {
                short8 a[4];
                #pragma unroll
                for (int mt = 0; mt < 4; ++mt)
                    a[mt] = *(const short8*)&Hb[mt * 16 + col][ks * 32 + kk];
                #pragma unroll
                for (int mt = 0; mt < 4; ++mt) {
                    acc[mt][0] = __builtin_amdgcn_mfma_f32_16x16x32_bf16(a[mt], wf[1][0][ks], acc[mt][0], 0, 0, 0);
                    acc[mt][1] = __builtin_amdgcn_mfma_f32_16x16x32_bf16(a[mt], wf[1][1][ks], acc[mt][1], 0, 0, 0);
                }
            }
            const int crow = (lane >> 4) * 4;
            #pragma unroll
            for (int mt = 0; mt < 4; ++mt)
                #pragma unroll
                for (int nt = 0; nt < 2; ++nt)
                    #pragma unroll
                    for (int r = 0; r < 4; ++r)
                        Ha[mt * 16 + crow + r][w * 32 + nt * 16 + col] = f2bf(softplus_f(acc[mt][nt][r]));
        }
        __syncthreads();

        // ======== output layer + slack ========
        {
            float s = 0.f;
            const float* wo = Wout + q * 32;
            const short8* hp = (const short8*)&Ha[p][q * 32];
            #pragma unroll
            for (int v = 0; v < 4; ++v) {
                short8 hh = hp[v];
                #pragma unroll
                for (int e = 0; e < 8; ++e)
                    s += bf2f((unsigned short)hh[e]) * wo[v * 8 + e];
            }
            s += __shfl_xor(s, 1);
            s += __shfl_xor(s, 2);
            if (q == 0) {
                float cost = 0.f;
                #pragma unroll
                for (int r = 0; r < 8; ++r) cost += Y_lds[rd][r] * U_lds[p][r];
                slk[p] = cost - (s + bo);
            }
        }
        __syncthreads();

        // ======== 64-j logsumexp partial for this (i, jb) ========
        {
            float v = slk[lane];
            float m = v;
            #pragma unroll
            for (int off = 32; off; off >>= 1) m = fmaxf(m, __shfl_xor(m, off));
            float e = __expf((v - m) * 10.0f);
            #pragma unroll
            for (int off = 32; off; off >>= 1) e += __shfl_xor(e, off);
            if (tid == 0) {
                part[((i0 + rd) * 16 + jb) * 2 + 0] = m;
                part[((i0 + rd) * 16 + jb) * 2 + 1] = e;
            }
        }
        __syncthreads();
    }
}

// ---------------- combine: merge 16 chunk partials per row ----------------
__global__ __launch_bounds__(256) void combine_kernel(
    const float* __restrict__ part, float* __restrict__ out)
{
    const int i = blockIdx.x * 256 + threadIdx.x;
    if (i >= 1024) return;
    float M = -1e30f;
    #pragma unroll
    for (int c = 0; c < 16; ++c) M = fmaxf(M, part[(i * 16 + c) * 2 + 0]);
    float S = 0.f;
    #pragma unroll
    for (int c = 0; c < 16; ++c)
        S += part[(i * 16 + c) * 2 + 1] * __expf((part[(i * 16 + c) * 2 + 0] - M) * 10.0f);
    out[i] = M + 0.1f * (logf(S) - 6.9314718055994531f);   // log(1024)
}

extern "C" void kernel_launch(void* const* d_in, const int* in_sizes, int n_in,
                              void* d_out, int out_size, void* d_ws, size_t ws_size,
                              hipStream_t stream) {
    const float* X    = (const float*)d_in[0];
    const float* Y    = (const float*)d_in[1];
    const float* U    = (const float*)d_in[2];
    const float* W0   = (const float*)d_in[3];
    const float* b0   = (const float*)d_in[4];
    const float* W1   = (const float*)d_in[5];
    const float* b1   = (const float*)d_in[6];
    const float* W2   = (const float*)d_in[7];
    const float* b2   = (const float*)d_in[8];
    const float* Wout = (const float*)d_in[9];
    const float* bout = (const float*)d_in[10];
    float* out = (float*)d_out;

    char* ws = (char*)d_ws;
    float*          A    = (float*)(ws);                                   // 512 KB
    float*          Bu   = (float*)(ws + (512 << 10));                     // 512 KB
    unsigned short* w1t  = (unsigned short*)(ws + (1024 << 10));           // 32 KB
    unsigned short* w2t  = (unsigned short*)(ws + (1024 << 10) + (32 << 10)); // 32 KB
    float*          part = (float*)(ws + (1024 << 10) + (64 << 10));       // 128 KB

    prep_kernel<<<2304, 128, 0, stream>>>(X, U, W0, b0, W1, W2, A, Bu, w1t, w2t);
    main_kernel<<<1024, 256, 0, stream>>>(A, Bu, w1t, w2t, Y, U, b1, b2, Wout, bout, part);
    combine_kernel<<<4, 256, 0, stream>>>(part, out);
}